// Round 5
// baseline (373.662 us; speedup 1.0000x reference)
//
#include <hip/hip_runtime.h>
#include <hip/hip_bf16.h>

// Problem dims: B=8, C=64, H=W=64, INTER=16. Attention branch is dead code
// (its result feeds only the discarded `_dead` tensor).
#define NPIX 4096
#define FEPS 1e-5f

typedef __hip_bfloat16 bf16;
typedef __attribute__((ext_vector_type(8))) short bf16x8;  // 8 bf16 = 4 VGPRs
typedef __attribute__((ext_vector_type(4))) short bf16x4;  // 4 bf16 = 2 VGPRs
typedef __attribute__((ext_vector_type(4))) float f32x4;   // MFMA 16x16 acc

// K=16 MFMA for gate layer-2 (C-layout of layer-1 == B-layout of K=16 MFMA).
// v_mfma_f32_16x16x16_bf16 (cdna4_isa.md §10); clang name is the gfx90a-era
// _1k builtin, carried forward on gfx950. Do NOT guard with __has_builtin:
// the HIP host pass checks the x86 target and returns 0 (R3 build failure).
#define MFMA16(A,B,C) __builtin_amdgcn_mfma_f32_16x16x16bf16_1k(A,B,C,0,0,0)

// ws layout:
//  word 0 (as int): dtype flag (1 = bf16, 2 = fp32), published by fused k1
//  float region (element offsets):
#define OFF_FOLD 64     // A1[16] B1[16] A2[64](@32) B2[64](@96) gA1(@160) gB1(@176) gA2(@192) gB2(@256) cA(@320) cB(@384)
#define OFF_G    512    // 512 floats: per (b,c) channel means
#define OFF_LW1  1024
#define OFF_LW2  2048   // stored TRANSPOSED [k][c] (16x64) by prep (slow path)
#define OFF_GW1  3072
#define OFF_GW2  4096   // float region ends at 5120 floats = 20480 B
//  byte offsets:
#define WSWZ_BYTES_OFF 20480    // 36864 ushort (73728 B): conv W in MFMA A-frag order
#define XO_BYTES_OFF   94208    // bf16 xo[8][4096 pix][64 ic] (pixel-major), 4 MB
#define GWF_BYTES_OFF  4288512  // gate W1/W2 MFMA A-frags, bf16: 1024 + 1024 elems

template<typename T> __device__ __forceinline__ float ldf(const T* p);
template<> __device__ __forceinline__ float ldf<bf16>(const bf16* p)  { return __bfloat162float(*p); }
template<> __device__ __forceinline__ float ldf<float>(const float* p){ return *p; }

template<typename T> __device__ __forceinline__ void stf(T* p, float v);
template<> __device__ __forceinline__ void stf<bf16>(bf16* p, float v)  { *p = __float2bfloat16(v); }
template<> __device__ __forceinline__ void stf<float>(float* p, float v){ *p = v; }

__device__ __forceinline__ unsigned short f2bu(float f) {
    union { bf16 h; unsigned short u; } c; c.h = __float2bfloat16(f); return c.u;
}
__device__ __forceinline__ float bu2f(unsigned short u) {
    union { unsigned i; float f; } c; c.i = ((unsigned)u) << 16; return c.f;
}
__device__ __forceinline__ float blo(unsigned u) {
    union { unsigned i; float f; } c; c.i = u << 16; return c.f;
}
__device__ __forceinline__ float bhi(unsigned u) {
    union { unsigned i; float f; } c; c.i = u & 0xffff0000u; return c.f;
}

// dtype probe: low 16 bits of each 32-bit word of N(0,1) bf16 data are a bf16
// value (exponent near 127); for fp32 data they are uniform mantissa bits.
__device__ __forceinline__ int probe_flag(const unsigned* __restrict__ x,
                                          int tid, int* sflag)
{
    if (tid < 64) {
        unsigned w = x[tid];
        unsigned h = w & 0xffffu;
        int e = (int)((h >> 7) & 0xff);
        int hit = (h == 0u || (e >= 96 && e <= 160)) ? 1 : 0;
        unsigned long long m = __ballot(hit);
        if (tid == 0) *sflag = (__popcll(m) >= 40) ? 1 : 2;  // bf16 ~64, fp32 ~16
    }
    __syncthreads();
    return *sflag;
}

// ---------------------------------------------------------------------------
struct PrepArgs7 { const void* p[30]; };
// slots: 0..5 lw1 lb1 ls1 lbb1 lm1 lv1 | 6..11 lw2 lb2 ls2 lbb2 lm2 lv2
//        12..17 gw1 gb1 gs1 gbb1 gm1 gv1 | 18..23 gw2 gb2 gs2 gbb2 gm2 gv2
//        24..29 cw cb cs cbb cm cv

// prep body: blocks 0..15 swizzle conv W into MFMA A-frag order; block 16
// copies MLP weights to fp32 (LW2 transposed); block 17 folds BN consts +
// publishes flag; block 18 swizzles gate W1/W2 into MFMA A-frag bf16 order:
//   W1frag[s][l][j] = lw1[i=l&15][c=s*32+(l>>4)*8+j]      (16x16x32 A-frag)
//   W2frag[g][l][j] = lw2[oc=g*16+(l&15)][k=(l>>4)*4+j]   (16x16x16 A-frag)
template<typename T>
__device__ void prep_body(const PrepArgs7& a, float* __restrict__ ws,
                          unsigned short* __restrict__ wswz,
                          unsigned short* __restrict__ gwf, int flag)
{
    const T* lw1  = (const T*)a.p[0];  const T* lb1  = (const T*)a.p[1];
    const T* ls1  = (const T*)a.p[2];  const T* lbb1 = (const T*)a.p[3];
    const T* lm1  = (const T*)a.p[4];  const T* lv1  = (const T*)a.p[5];
    const T* lw2  = (const T*)a.p[6];  const T* lb2  = (const T*)a.p[7];
    const T* ls2  = (const T*)a.p[8];  const T* lbb2 = (const T*)a.p[9];
    const T* lm2  = (const T*)a.p[10]; const T* lv2  = (const T*)a.p[11];
    const T* gw1  = (const T*)a.p[12]; const T* gb1  = (const T*)a.p[13];
    const T* gs1  = (const T*)a.p[14]; const T* gbb1 = (const T*)a.p[15];
    const T* gm1  = (const T*)a.p[16]; const T* gv1  = (const T*)a.p[17];
    const T* gw2  = (const T*)a.p[18]; const T* gb2  = (const T*)a.p[19];
    const T* gs2  = (const T*)a.p[20]; const T* gbb2 = (const T*)a.p[21];
    const T* gm2  = (const T*)a.p[22]; const T* gv2  = (const T*)a.p[23];
    const T* cw   = (const T*)a.p[24]; const T* cb   = (const T*)a.p[25];
    const T* cs   = (const T*)a.p[26]; const T* cbb  = (const T*)a.p[27];
    const T* cm   = (const T*)a.p[28]; const T* cv   = (const T*)a.p[29];

    int bx = blockIdx.x;
    int tid = threadIdx.x;
    if (bx < 16) {
        for (int e = tid; e < 2304; e += 256) {
            int E = bx * 2304 + e;
            int j = E & 7;
            int F = E >> 3;
            int l = F & 63;
            int g = (F >> 6) & 3;
            int ts = F >> 8;          // t*2+s
            int s = ts & 1;
            int t = ts >> 1;
            int oc = g * 16 + (l & 15);
            int ic = s * 32 + (l >> 4) * 8 + j;
            wswz[E] = f2bu(ldf(cw + (oc * 64 + ic) * 9 + t));
        }
    } else if (bx == 16) {
        for (int e = tid; e < 4096; e += 256) {
            if (e < 1024)      ws[OFF_LW1 + e]        = ldf(lw1 + e);
            else if (e < 2048) {
                int F = e - 1024;          // lw2 is [c=64][k=16] row-major
                int c = F >> 4;
                int k = F & 15;
                ws[OFF_LW2 + k * 64 + c] = ldf(lw2 + F);   // store [k][c]
            }
            else if (e < 3072) ws[OFF_GW1 + e - 2048] = ldf(gw1 + e - 2048);
            else               ws[OFF_GW2 + e - 3072] = ldf(gw2 + e - 3072);
        }
    } else if (bx == 17) {
        if (tid == 0) ((int*)ws)[0] = flag;   // publish for gate/conv kernels
        if (tid < 16) {
            float inv = ldf(ls1 + tid) * rsqrtf(ldf(lv1 + tid) + FEPS);
            ws[OFF_FOLD + 0  + tid] = inv;
            ws[OFF_FOLD + 16 + tid] = ldf(lb1 + tid) * inv + ldf(lbb1 + tid) - ldf(lm1 + tid) * inv;
            float ginv = ldf(gs1 + tid) * rsqrtf(ldf(gv1 + tid) + FEPS);
            ws[OFF_FOLD + 160 + tid] = ginv;
            ws[OFF_FOLD + 176 + tid] = ldf(gb1 + tid) * ginv + ldf(gbb1 + tid) - ldf(gm1 + tid) * ginv;
        }
        if (tid < 64) {
            float inv2 = ldf(ls2 + tid) * rsqrtf(ldf(lv2 + tid) + FEPS);
            ws[OFF_FOLD + 32 + tid] = inv2;
            ws[OFF_FOLD + 96 + tid] = ldf(lb2 + tid) * inv2 + ldf(lbb2 + tid) - ldf(lm2 + tid) * inv2;
            float ginv2 = ldf(gs2 + tid) * rsqrtf(ldf(gv2 + tid) + FEPS);
            ws[OFF_FOLD + 192 + tid] = ginv2;
            ws[OFF_FOLD + 256 + tid] = ldf(gb2 + tid) * ginv2 + ldf(gbb2 + tid) - ldf(gm2 + tid) * ginv2;
            float cinv = ldf(cs + tid) * rsqrtf(ldf(cv + tid) + FEPS);
            ws[OFF_FOLD + 320 + tid] = cinv;
            ws[OFF_FOLD + 384 + tid] = ldf(cb + tid) * cinv + ldf(cbb + tid) - ldf(cm + tid) * cinv;
        }
    } else {   // bx == 18: gate MFMA weight frags (bf16)
        for (int e = tid; e < 2048; e += 256) {
            if (e < 1024) {
                int j = e & 7;
                int l = (e >> 3) & 63;
                int s = e >> 9;
                gwf[e] = f2bu(ldf(lw1 + (l & 15) * 64 + s * 32 + (l >> 4) * 8 + j));
            } else {
                int e2 = e - 1024;
                int j = e2 & 3;
                int l = (e2 >> 2) & 63;
                int g = e2 >> 8;
                gwf[e] = f2bu(ldf(lw2 + (g * 16 + (l & 15)) * 16 + (l >> 4) * 4 + j));
            }
        }
    }
}

// ---------------------------------------------------------------------------
// fused k1: grid 531 x 256. Every block self-probes the dtype (cheap, L2-hot).
//  blocks 0..18  : prep (conv/gate weight swizzle / MLP weights / folds + flag)
//  blocks 19..530: channel mean for bc = bx-19 (vectorized loads)
// ---------------------------------------------------------------------------
__global__ void r9_prep_means(PrepArgs7 a, const void* __restrict__ xv,
                              float* __restrict__ ws,
                              unsigned short* __restrict__ wswz,
                              unsigned short* __restrict__ gwf)
{
    __shared__ int sflag;
    int t = threadIdx.x;
    int flag = probe_flag((const unsigned*)xv, t, &sflag);
    int bx = blockIdx.x;

    if (bx < 19) {
        if (flag == 1) prep_body<bf16>(a, ws, wswz, gwf, flag);
        else           prep_body<float>(a, ws, wswz, gwf, flag);
        return;
    }

    int bc = bx - 19;
    float s = 0.f;
    if (flag == 1) {
        const uint4* p = (const uint4*)((const bf16*)xv + (size_t)bc * NPIX);
#pragma unroll
        for (int i = 0; i < 2; ++i) {
            uint4 v = p[t * 2 + i];
            s += blo(v.x) + bhi(v.x) + blo(v.y) + bhi(v.y)
               + blo(v.z) + bhi(v.z) + blo(v.w) + bhi(v.w);
        }
    } else {
        const float4* p = (const float4*)((const float*)xv + (size_t)bc * NPIX);
#pragma unroll
        for (int i = 0; i < 4; ++i) {
            float4 v = p[t * 4 + i];
            s += v.x + v.y + v.z + v.w;
        }
    }
#pragma unroll
    for (int off = 32; off > 0; off >>= 1) s += __shfl_down(s, off, 64);
    __shared__ float red[4];
    if ((t & 63) == 0) red[t >> 6] = s;
    __syncthreads();
    if (t == 0)
        ws[OFF_G + bc] = (red[0] + red[1] + red[2] + red[3]) * (1.0f / 4096.0f);
}

// ---------------------------------------------------------------------------
// gate slow path (fp32 insurance): one pixel per thread (tid<64 active).
// grid 512 x 128: block = 64 px of one image.
// ---------------------------------------------------------------------------
__device__ void gate_slow_f32(const void* __restrict__ xv, float* __restrict__ ws,
                              uint4* __restrict__ xo)
{
    int bx = blockIdx.x;
    int b = bx >> 6;
    int tid = threadIdx.x;

    __shared__ float t1[16];
    __shared__ float xg[64];
    if (tid < 16) {
        float s = 0.f;
#pragma unroll
        for (int c = 0; c < 64; ++c)
            s += ws[OFF_GW1 + tid * 64 + c] * ws[OFF_G + b * 64 + c];
        t1[tid] = fmaxf(ws[OFF_FOLD + 160 + tid] * s + ws[OFF_FOLD + 176 + tid], 0.f);
    }
    __syncthreads();
    if (tid < 64) {
        float s = 0.f;
#pragma unroll
        for (int j = 0; j < 16; ++j) s += ws[OFF_GW2 + tid * 16 + j] * t1[j];
        xg[tid] = ws[OFF_FOLD + 192 + tid] * s + ws[OFF_FOLD + 256 + tid];
    }
    __syncthreads();
    if (tid >= 64) return;
    int n = (bx & 63) * 64 + tid;

    const float* xb = (const float*)xv + (size_t)b * 64 * NPIX + n;
    float xr[64];
#pragma unroll
    for (int c = 0; c < 64; ++c) xr[c] = xb[c * NPIX];

    float h[16];
#pragma unroll
    for (int i = 0; i < 16; ++i) {
        float s = 0.f;
#pragma unroll
        for (int c = 0; c < 64; ++c) s += ws[OFF_LW1 + i * 64 + c] * xr[c];
        h[i] = fmaxf(ws[OFF_FOLD + 0 + i] * s + ws[OFF_FOLD + 16 + i], 0.f);
    }

    uint4* xop = xo + ((size_t)b * NPIX + n) * 8;
#pragma unroll
    for (int cg = 0; cg < 8; ++cg) {
        unsigned v[8];
#pragma unroll
        for (int j = 0; j < 8; ++j) {
            int c = cg * 8 + j;
            float s = 0.f;
#pragma unroll
            for (int k = 0; k < 16; ++k) s += ws[OFF_LW2 + k * 64 + c] * h[k];
            float z = ws[OFF_FOLD + 32 + c] * s + ws[OFF_FOLD + 96 + c] + xg[c];
            v[j] = (unsigned)f2bu(xr[c] / (1.0f + __expf(-z)));
        }
        uint4 pk;
        pk.x = v[0] | (v[1] << 16);
        pk.y = v[2] | (v[3] << 16);
        pk.z = v[4] | (v[5] << 16);
        pk.w = v[6] | (v[7] << 16);
        xop[cg] = pk;
    }
}

// ---------------------------------------------------------------------------
// gate fast path (bf16): weight-stationary MFMA. grid 512 x 128 (2 waves);
// block = 64 px of one image, wave w owns px [w*32, w*32+32) as two 16-px
// MFMA column tiles.
//   layer1: acc(4f32) = mfma_16x16x32(W1frag_s, Xfrag_s)  s=0,1  (K=64)
//           H C-layout: row i=(l>>4)*4+reg, col px=l&15
//   layer2: H's C-layout IS the B-layout of mfma_16x16x16 -> in-lane relu+cvt,
//           4 MFMAs (oc groups) -> Z[c=g*16+4q+reg][px=a], 16 z/lane
// Weights live in 16 VGPRs (pre-swizzled by prep block 18), loaded once.
// X gathered directly from global (u16, 4x32B segments/instr, L2/L1-hot);
// no x LDS tile, no pack round-trip. Stores: per (tile,g) one dwordx2
// (4 adjacent bf16 channels) into pixel-major xo.
// Rationale (R2 post-mortem): gate was latency-bound (VALUBusy 17%, HBM 2%,
// ~600 dependent long-latency ops/thread at 1-2 waves/SIMD). This cuts
// long-latency ops ~6x and replaces 4096 serial FMAs with 12 MFMAs.
// ---------------------------------------------------------------------------
__global__ __launch_bounds__(128)
void r9_gate(const void* __restrict__ xv, float* __restrict__ ws,
             uint4* __restrict__ xo)
{
    if (((const int*)ws)[0] != 1) { gate_slow_f32(xv, ws, xo); return; }

    int bx = blockIdx.x;
    int b   = bx >> 6;
    int tid = threadIdx.x;
    int w   = tid >> 6;
    int l   = tid & 63;
    int a   = l & 15;
    int q   = l >> 4;

    __shared__ float t1[16];
    __shared__ float xgs[64];

    // ---- weight frags (issue first; independent of everything)
    const unsigned short* gwf =
        (const unsigned short*)((const char*)ws + GWF_BYTES_OFF);
    bf16x8 W1f0 = ((const bf16x8*)gwf)[l];
    bf16x8 W1f1 = ((const bf16x8*)gwf)[64 + l];
    const bf16x4* wf2 = (const bf16x4*)(gwf + 1024);
    bf16x4 W2f0 = wf2[l];
    bf16x4 W2f1 = wf2[64 + l];
    bf16x4 W2f2 = wf2[128 + l];
    bf16x4 W2f3 = wf2[192 + l];

    // ---- per-lane fold consts: layer1 rows i=4q+reg, layer2 ch c=g*16+4q+reg
    float A1v[4], B1v[4];
#pragma unroll
    for (int reg = 0; reg < 4; ++reg) {
        A1v[reg] = ws[OFF_FOLD + 0  + 4 * q + reg];
        B1v[reg] = ws[OFF_FOLD + 16 + 4 * q + reg];
    }
    float A2v[4][4], B2v[4][4];
#pragma unroll
    for (int g = 0; g < 4; ++g)
#pragma unroll
        for (int reg = 0; reg < 4; ++reg) {
            int c = g * 16 + 4 * q + reg;
            A2v[g][reg] = ws[OFF_FOLD + 32 + c];
            B2v[g][reg] = ws[OFF_FOLD + 96 + c];
        }

    // ---- block-cooperative global-MLP (xg), same as proven r7 pattern
    if (tid < 16) {
        float s = 0.f;
#pragma unroll
        for (int c = 0; c < 64; ++c)
            s += ws[OFF_GW1 + tid * 64 + c] * ws[OFF_G + b * 64 + c];
        t1[tid] = fmaxf(ws[OFF_FOLD + 160 + tid] * s + ws[OFF_FOLD + 176 + tid], 0.f);
    }
    __syncthreads();
    if (tid < 64) {
        float s = 0.f;
#pragma unroll
        for (int j = 0; j < 16; ++j) s += ws[OFF_GW2 + tid * 16 + j] * t1[j];
        xgs[tid] = ws[OFF_FOLD + 192 + tid] * s + ws[OFF_FOLD + 256 + tid];
    }
    __syncthreads();

    float xgv[4][4];
#pragma unroll
    for (int g = 0; g < 4; ++g)
#pragma unroll
        for (int reg = 0; reg < 4; ++reg)
            xgv[g][reg] = xgs[g * 16 + 4 * q + reg];

    const unsigned short* xb = (const unsigned short*)xv + (size_t)b * 64 * NPIX;
    char* xob = (char*)xo + (size_t)b * NPIX * 128;
    const f32x4 zz = {0.f, 0.f, 0.f, 0.f};
    int pxb0 = (bx & 63) * 64 + w * 32;

#pragma unroll
    for (int tile = 0; tile < 2; ++tile) {
        int pxl = pxb0 + tile * 16 + a;

        // B-frag gather: lane holds X[c = s*32 + q*8 + j][pxl]
        unsigned short g0[8], g1[8];
#pragma unroll
        for (int j = 0; j < 8; ++j) {
            g0[j] = xb[(q * 8 + j) * NPIX + pxl];
            g1[j] = xb[(32 + q * 8 + j) * NPIX + pxl];
        }
        bf16x8 B0 = { (short)g0[0], (short)g0[1], (short)g0[2], (short)g0[3],
                      (short)g0[4], (short)g0[5], (short)g0[6], (short)g0[7] };
        bf16x8 B1 = { (short)g1[0], (short)g1[1], (short)g1[2], (short)g1[3],
                      (short)g1[4], (short)g1[5], (short)g1[6], (short)g1[7] };

        f32x4 acc = __builtin_amdgcn_mfma_f32_16x16x32_bf16(W1f0, B0, zz, 0, 0, 0);
        acc = __builtin_amdgcn_mfma_f32_16x16x32_bf16(W1f1, B1, acc, 0, 0, 0);

        // relu + BN fold, convert in-lane to layer-2 B-frag (k = 4q+j <-> reg)
        bf16x4 Hf = { (short)f2bu(fmaxf(acc[0] * A1v[0] + B1v[0], 0.f)),
                      (short)f2bu(fmaxf(acc[1] * A1v[1] + B1v[1], 0.f)),
                      (short)f2bu(fmaxf(acc[2] * A1v[2] + B1v[2], 0.f)),
                      (short)f2bu(fmaxf(acc[3] * A1v[3] + B1v[3], 0.f)) };

        f32x4 z0 = MFMA16(W2f0, Hf, zz);
        f32x4 z1 = MFMA16(W2f1, Hf, zz);
        f32x4 z2 = MFMA16(W2f2, Hf, zz);
        f32x4 z3 = MFMA16(W2f3, Hf, zz);

        // gating + packed stores: per g, 4 adjacent channels -> one dwordx2
        char* rec = xob + (size_t)pxl * 128 + q * 8;
#pragma unroll
        for (int g = 0; g < 4; ++g) {
            const f32x4& zf = (g == 0) ? z0 : (g == 1) ? z1 : (g == 2) ? z2 : z3;
            unsigned vv[4];
#pragma unroll
            for (int reg = 0; reg < 4; ++reg) {
                int c = g * 16 + 4 * q + reg;
                float zval = zf[reg] * A2v[g][reg] + B2v[g][reg] + xgv[g][reg];
                float xval = bu2f(xb[c * NPIX + pxl]);
                vv[reg] = (unsigned)f2bu(xval / (1.0f + __expf(-zval)));
            }
            uint2 pk;
            pk.x = vv[0] | (vv[1] << 16);
            pk.y = vv[2] | (vv[3] << 16);
            *(uint2*)(rec + g * 32) = pk;
        }
    }
}

// ---------------------------------------------------------------------------
// conv3x3 as implicit GEMM on MFMA 16x16x32 bf16 (unchanged, proven).
// Tile: 32 pixels (half image-row) x 64 oc. WG = 128 thr = 2 waves; wave w
// handles oc groups {2w, 2w+1}. Grid = 8 img * 64 rows * 2 halves = 1024 WGs.
// xo B-operands staged in LDS (3 rows x 34 px x 128 B, XOR-swizzled
// byte ^= (px&7)<<4) with zero-filled column halos; conflict-free ds_read_b128.
// C/D layout (m89): col(n=pixel)=lane&15, row(m=oc)=(lane>>4)*4+reg.
// ---------------------------------------------------------------------------
#define CONV_LDS_BYTES (3 * 34 * 128)   // 13056 B

template<typename T>
__device__ void conv_body(const bf16x8* __restrict__ wsw, const float* __restrict__ ws,
                          const char* __restrict__ xob_base, void* __restrict__ outv,
                          char* __restrict__ lds)
{
    int bx  = blockIdx.x;
    int b   = bx >> 7;
    int r   = (bx >> 1) & 63;
    int c0  = (bx & 1) * 32;
    int tid = threadIdx.x;
    int w   = tid >> 6;
    int l   = tid & 63;
    int a   = l & 15;
    int q   = l >> 4;

    const char* xob = xob_base + (size_t)b * NPIX * 128;  // 128 B per pixel

    // ---- stage 3 rows x 34 px (cols c0-1 .. c0+32) of xo, halo cols zeroed.
    for (int e = tid; e < 816; e += 128) {
        int row = e / 272;            // 0..2  (272 = 34 px * 8 chunks)
        int rm  = e - row * 272;
        int px  = rm >> 3;            // 0..33
        int u   = rm & 7;
        int col = c0 - 1 + px;
        int rr  = r - 1 + row;
        uint4 v = {0u, 0u, 0u, 0u};
        if (col >= 0 && col <= 63) {
            int rc = min(63, max(0, rr));   // clamped rows: data unused (tap skipped)
            v = *(const uint4*)(xob + rc * 8192 + col * 128 + u * 16);
        }
        int byt = ((row * 34 + px) * 128 + u * 16) ^ ((px & 7) << 4);
        *(uint4*)(lds + byt) = v;
    }
    __syncthreads();

    f32x4 acc[2][2] = {};   // [oc-group-half][pixel-nf]

#pragma unroll
    for (int t = 0; t < 9; ++t) {
        const int dr  = t / 3 - 1;
        const int dci = t % 3;
        int rr = r + dr;
        if (rr < 0 || rr > 63) continue;           // uniform per WG
        const char* rowp = lds + (dr + 1) * (34 * 128);
#pragma unroll
        for (int s = 0; s < 2; ++s) {
            bf16x8 A0 = wsw[((t * 2 + s) * 4 + 2 * w + 0) * 64 + l];
            bf16x8 A1 = wsw[((t * 2 + s) * 4 + 2 * w + 1) * 64 + l];
            int sq = s * 64 + q * 16;
#pragma unroll
            for (int nf = 0; nf < 2; ++nf) {
                int tp  = nf * 16 + a + dci;       // tile pixel 0..33
                int byt = tp * 128 + (sq ^ ((tp & 7) << 4));
                bf16x8 B = *(const bf16x8*)(rowp + byt);
                acc[0][nf] = __builtin_amdgcn_mfma_f32_16x16x32_bf16(A0, B, acc[0][nf], 0, 0, 0);
                acc[1][nf] = __builtin_amdgcn_mfma_f32_16x16x32_bf16(A1, B, acc[1][nf], 0, 0, 0);
            }
        }
    }

    const float* cA = ws + OFF_FOLD + 320;
    const float* cB = ws + OFF_FOLD + 384;
    int pixBase = r * 64 + c0;
#pragma unroll
    for (int gi = 0; gi < 2; ++gi) {
        int g = 2 * w + gi;
#pragma unroll
        for (int reg = 0; reg < 4; ++reg) {
            int oc = g * 16 + q * 4 + reg;
            float Af = cA[oc];
            float Bf = cB[oc];
#pragma unroll
            for (int nf = 0; nf < 2; ++nf) {
                int pix = pixBase + nf * 16 + a;
                float y = fmaxf(acc[gi][nf][reg] * Af + Bf, 0.f);
                stf((T*)outv + ((size_t)b * 64 + oc) * NPIX + pix, y);
            }
        }
    }
}

__global__ __launch_bounds__(128)
void r9_conv(const bf16x8* __restrict__ wsw, const float* __restrict__ ws,
             const char* __restrict__ xob_base, void* __restrict__ outv)
{
    __shared__ char lds[CONV_LDS_BYTES];
    if (((const int*)ws)[0] == 1) conv_body<bf16>(wsw, ws, xob_base, outv, lds);
    else                          conv_body<float>(wsw, ws, xob_base, outv, lds);
}

// ---------------------------------------------------------------------------
extern "C" void kernel_launch(void* const* d_in, const int* in_sizes, int n_in,
                              void* d_out, int out_size, void* d_ws, size_t ws_size,
                              hipStream_t stream)
{
    (void)in_sizes; (void)n_in; (void)out_size; (void)ws_size;
    const void* x = d_in[0];
    float* ws = (float*)d_ws;
    unsigned short* wswz = (unsigned short*)((char*)d_ws + WSWZ_BYTES_OFF);
    unsigned short* gwf  = (unsigned short*)((char*)d_ws + GWF_BYTES_OFF);
    char* xo = (char*)d_ws + XO_BYTES_OFF;

    PrepArgs7 pa;
    // lw1..lv2 = d_in[1..12], gw1..gv2 = d_in[13..24]
    for (int i = 0; i < 24; ++i) pa.p[i] = d_in[1 + i];
    // d_in[25..31]: qw qb kw kb vw vb gamma -> dead code (attention output discarded)
    for (int i = 0; i < 6; ++i)  pa.p[24 + i] = d_in[32 + i];

    r9_prep_means<<<dim3(531), dim3(256), 0, stream>>>(pa, x, ws, wswz, gwf);
    r9_gate<<<dim3(512), dim3(128), 0, stream>>>(x, ws, (uint4*)xo);
    r9_conv<<<dim3(1024), dim3(128), 0, stream>>>(
        (const bf16x8*)wswz, ws, xo, d_out);
}

// Round 6
// 221.723 us; speedup vs baseline: 1.6853x; 1.6853x over previous
//
#include <hip/hip_runtime.h>
#include <hip/hip_bf16.h>

// Problem dims: B=8, C=64, H=W=64, INTER=16. Attention branch is dead code
// (its result feeds only the discarded `_dead` tensor).
#define NPIX 4096
#define FEPS 1e-5f

typedef __hip_bfloat16 bf16;
typedef __attribute__((ext_vector_type(8))) short bf16x8;  // 8 bf16 = 4 VGPRs
typedef __attribute__((ext_vector_type(4))) short bf16x4;  // 4 bf16 = 2 VGPRs
typedef __attribute__((ext_vector_type(4))) float f32x4;   // MFMA 16x16 acc

// K=16 MFMA for gate layer-2 (C-layout of layer-1 == B-layout of K=16 MFMA).
// Do NOT guard with __has_builtin: HIP host pass checks x86 (R3 failure).
#define MFMA16(A,B,C) __builtin_amdgcn_mfma_f32_16x16x16bf16_1k(A,B,C,0,0,0)

// ws layout:
//  word 0 (as int): dtype flag (1 = bf16, 2 = fp32), published by fused k1
//  float region (element offsets):
#define OFF_FOLD 64     // A1[16] B1[16] A2[64](@32) B2[64](@96) gA1(@160) gB1(@176) gA2(@192) gB2(@256) cA(@320) cB(@384)
#define OFF_G    512    // 512 floats: per (b,c) channel means
#define OFF_LW1  1024
#define OFF_LW2  2048   // stored TRANSPOSED [k][c] (16x64) by prep (slow path)
#define OFF_GW1  3072
#define OFF_GW2  4096   // float region ends at 5120 floats = 20480 B
//  byte offsets:
#define WSWZ_BYTES_OFF 20480    // 36864 ushort (73728 B): conv W in MFMA A-frag order
#define XO_BYTES_OFF   94208    // bf16 xo[8][4096 pix][64 ic] (pixel-major), 4 MB
#define GWF_BYTES_OFF  4288512  // gate W1/W2 MFMA A-frags, bf16: 1024+1024 elems
#define XG_BYTES_OFF   4292608  // xg[8][64] fp32 (2 KB), written by r10_xg

template<typename T> __device__ __forceinline__ float ldf(const T* p);
template<> __device__ __forceinline__ float ldf<bf16>(const bf16* p)  { return __bfloat162float(*p); }
template<> __device__ __forceinline__ float ldf<float>(const float* p){ return *p; }

template<typename T> __device__ __forceinline__ void stf(T* p, float v);
template<> __device__ __forceinline__ void stf<bf16>(bf16* p, float v)  { *p = __float2bfloat16(v); }
template<> __device__ __forceinline__ void stf<float>(float* p, float v){ *p = v; }

__device__ __forceinline__ unsigned short f2bu(float f) {
    union { bf16 h; unsigned short u; } c; c.h = __float2bfloat16(f); return c.u;
}
__device__ __forceinline__ float bu2f(unsigned short u) {
    union { unsigned i; float f; } c; c.i = ((unsigned)u) << 16; return c.f;
}
__device__ __forceinline__ float blo(unsigned u) {
    union { unsigned i; float f; } c; c.i = u << 16; return c.f;
}
__device__ __forceinline__ float bhi(unsigned u) {
    union { unsigned i; float f; } c; c.i = u & 0xffff0000u; return c.f;
}

// dtype probe: low 16 bits of each 32-bit word of N(0,1) bf16 data are a bf16
// value (exponent near 127); for fp32 data they are uniform mantissa bits.
__device__ __forceinline__ int probe_flag(const unsigned* __restrict__ x,
                                          int tid, int* sflag)
{
    if (tid < 64) {
        unsigned w = x[tid];
        unsigned h = w & 0xffffu;
        int e = (int)((h >> 7) & 0xff);
        int hit = (h == 0u || (e >= 96 && e <= 160)) ? 1 : 0;
        unsigned long long m = __ballot(hit);
        if (tid == 0) *sflag = (__popcll(m) >= 40) ? 1 : 2;  // bf16 ~64, fp32 ~16
    }
    __syncthreads();
    return *sflag;
}

// ---------------------------------------------------------------------------
struct PrepArgs7 { const void* p[30]; };
// slots: 0..5 lw1 lb1 ls1 lbb1 lm1 lv1 | 6..11 lw2 lb2 ls2 lbb2 lm2 lv2
//        12..17 gw1 gb1 gs1 gbb1 gm1 gv1 | 18..23 gw2 gb2 gs2 gbb2 gm2 gv2
//        24..29 cw cb cs cbb cm cv

// prep body: blocks 0..15 swizzle conv W into MFMA A-frag order; block 16
// copies MLP weights to fp32 (LW2 transposed); block 17 folds BN consts +
// publishes flag; block 18 swizzles gate W1/W2 into MFMA A-frag bf16 order:
//   W1frag[s][l][j] = lw1[i=l&15][c=s*32+(l>>4)*8+j]      (16x16x32 A-frag)
//   W2frag[g][l][j] = lw2[oc=g*16+(l&15)][k=(l>>4)*4+j]   (16x16x16 A-frag)
template<typename T>
__device__ void prep_body(const PrepArgs7& a, float* __restrict__ ws,
                          unsigned short* __restrict__ wswz,
                          unsigned short* __restrict__ gwf, int flag)
{
    const T* lw1  = (const T*)a.p[0];  const T* lb1  = (const T*)a.p[1];
    const T* ls1  = (const T*)a.p[2];  const T* lbb1 = (const T*)a.p[3];
    const T* lm1  = (const T*)a.p[4];  const T* lv1  = (const T*)a.p[5];
    const T* lw2  = (const T*)a.p[6];  const T* lb2  = (const T*)a.p[7];
    const T* ls2  = (const T*)a.p[8];  const T* lbb2 = (const T*)a.p[9];
    const T* lm2  = (const T*)a.p[10]; const T* lv2  = (const T*)a.p[11];
    const T* gw1  = (const T*)a.p[12]; const T* gb1  = (const T*)a.p[13];
    const T* gs1  = (const T*)a.p[14]; const T* gbb1 = (const T*)a.p[15];
    const T* gm1  = (const T*)a.p[16]; const T* gv1  = (const T*)a.p[17];
    const T* gw2  = (const T*)a.p[18]; const T* gb2  = (const T*)a.p[19];
    const T* gs2  = (const T*)a.p[20]; const T* gbb2 = (const T*)a.p[21];
    const T* gm2  = (const T*)a.p[22]; const T* gv2  = (const T*)a.p[23];
    const T* cw   = (const T*)a.p[24]; const T* cb   = (const T*)a.p[25];
    const T* cs   = (const T*)a.p[26]; const T* cbb  = (const T*)a.p[27];
    const T* cm   = (const T*)a.p[28]; const T* cv   = (const T*)a.p[29];

    int bx = blockIdx.x;
    int tid = threadIdx.x;
    if (bx < 16) {
        for (int e = tid; e < 2304; e += 256) {
            int E = bx * 2304 + e;
            int j = E & 7;
            int F = E >> 3;
            int l = F & 63;
            int g = (F >> 6) & 3;
            int ts = F >> 8;          // t*2+s
            int s = ts & 1;
            int t = ts >> 1;
            int oc = g * 16 + (l & 15);
            int ic = s * 32 + (l >> 4) * 8 + j;
            wswz[E] = f2bu(ldf(cw + (oc * 64 + ic) * 9 + t));
        }
    } else if (bx == 16) {
        for (int e = tid; e < 4096; e += 256) {
            if (e < 1024)      ws[OFF_LW1 + e]        = ldf(lw1 + e);
            else if (e < 2048) {
                int F = e - 1024;          // lw2 is [c=64][k=16] row-major
                int c = F >> 4;
                int k = F & 15;
                ws[OFF_LW2 + k * 64 + c] = ldf(lw2 + F);   // store [k][c]
            }
            else if (e < 3072) ws[OFF_GW1 + e - 2048] = ldf(gw1 + e - 2048);
            else               ws[OFF_GW2 + e - 3072] = ldf(gw2 + e - 3072);
        }
    } else if (bx == 17) {
        if (tid == 0) ((int*)ws)[0] = flag;   // publish for gate/conv kernels
        if (tid < 16) {
            float inv = ldf(ls1 + tid) * rsqrtf(ldf(lv1 + tid) + FEPS);
            ws[OFF_FOLD + 0  + tid] = inv;
            ws[OFF_FOLD + 16 + tid] = ldf(lb1 + tid) * inv + ldf(lbb1 + tid) - ldf(lm1 + tid) * inv;
            float ginv = ldf(gs1 + tid) * rsqrtf(ldf(gv1 + tid) + FEPS);
            ws[OFF_FOLD + 160 + tid] = ginv;
            ws[OFF_FOLD + 176 + tid] = ldf(gb1 + tid) * ginv + ldf(gbb1 + tid) - ldf(gm1 + tid) * ginv;
        }
        if (tid < 64) {
            float inv2 = ldf(ls2 + tid) * rsqrtf(ldf(lv2 + tid) + FEPS);
            ws[OFF_FOLD + 32 + tid] = inv2;
            ws[OFF_FOLD + 96 + tid] = ldf(lb2 + tid) * inv2 + ldf(lbb2 + tid) - ldf(lm2 + tid) * inv2;
            float ginv2 = ldf(gs2 + tid) * rsqrtf(ldf(gv2 + tid) + FEPS);
            ws[OFF_FOLD + 192 + tid] = ginv2;
            ws[OFF_FOLD + 256 + tid] = ldf(gb2 + tid) * ginv2 + ldf(gbb2 + tid) - ldf(gm2 + tid) * ginv2;
            float cinv = ldf(cs + tid) * rsqrtf(ldf(cv + tid) + FEPS);
            ws[OFF_FOLD + 320 + tid] = cinv;
            ws[OFF_FOLD + 384 + tid] = ldf(cb + tid) * cinv + ldf(cbb + tid) - ldf(cm + tid) * cinv;
        }
    } else {   // bx == 18: gate MFMA weight frags (bf16)
        for (int e = tid; e < 2048; e += 256) {
            if (e < 1024) {
                int j = e & 7;
                int l = (e >> 3) & 63;
                int s = e >> 9;
                gwf[e] = f2bu(ldf(lw1 + (l & 15) * 64 + s * 32 + (l >> 4) * 8 + j));
            } else {
                int e2 = e - 1024;
                int j = e2 & 3;
                int l = (e2 >> 2) & 63;
                int g = e2 >> 8;
                gwf[e] = f2bu(ldf(lw2 + (g * 16 + (l & 15)) * 16 + (l >> 4) * 4 + j));
            }
        }
    }
}

// ---------------------------------------------------------------------------
// fused k1: grid 531 x 256. Every block self-probes the dtype (cheap, L2-hot).
//  blocks 0..18  : prep (conv/gate weight swizzle / MLP weights / folds + flag)
//  blocks 19..530: channel mean for bc = bx-19 (vectorized loads)
// ---------------------------------------------------------------------------
__global__ void r10_prep_means(PrepArgs7 a, const void* __restrict__ xv,
                               float* __restrict__ ws,
                               unsigned short* __restrict__ wswz,
                               unsigned short* __restrict__ gwf)
{
    __shared__ int sflag;
    int t = threadIdx.x;
    int flag = probe_flag((const unsigned*)xv, t, &sflag);
    int bx = blockIdx.x;

    if (bx < 19) {
        if (flag == 1) prep_body<bf16>(a, ws, wswz, gwf, flag);
        else           prep_body<float>(a, ws, wswz, gwf, flag);
        return;
    }

    int bc = bx - 19;
    float s = 0.f;
    if (flag == 1) {
        const uint4* p = (const uint4*)((const bf16*)xv + (size_t)bc * NPIX);
#pragma unroll
        for (int i = 0; i < 2; ++i) {
            uint4 v = p[t * 2 + i];
            s += blo(v.x) + bhi(v.x) + blo(v.y) + bhi(v.y)
               + blo(v.z) + bhi(v.z) + blo(v.w) + bhi(v.w);
        }
    } else {
        const float4* p = (const float4*)((const float*)xv + (size_t)bc * NPIX);
#pragma unroll
        for (int i = 0; i < 4; ++i) {
            float4 v = p[t * 4 + i];
            s += v.x + v.y + v.z + v.w;
        }
    }
#pragma unroll
    for (int off = 32; off > 0; off >>= 1) s += __shfl_down(s, off, 64);
    __shared__ float red[4];
    if ((t & 63) == 0) red[t >> 6] = s;
    __syncthreads();
    if (t == 0)
        ws[OFF_G + bc] = (red[0] + red[1] + red[2] + red[3]) * (1.0f / 4096.0f);
}

// ---------------------------------------------------------------------------
// xg one-shot (R5 post-mortem): the global-branch MLP depends only on per-image
// means -> compute ONCE (8 blocks x 64 thr) instead of serially in every gate
// block (which cost 2 barriers + 16-lane serial chains x 512 blocks at 1
// wave/SIMD). Dtype-agnostic: reads prep's fp32 copies.
// ---------------------------------------------------------------------------
__global__ void r10_xg(float* __restrict__ ws)
{
    int b = blockIdx.x;
    int t = threadIdx.x;
    __shared__ float t1[16];
    if (t < 16) {
        float s = 0.f;
#pragma unroll
        for (int c = 0; c < 64; ++c)
            s += ws[OFF_GW1 + t * 64 + c] * ws[OFF_G + b * 64 + c];
        t1[t] = fmaxf(ws[OFF_FOLD + 160 + t] * s + ws[OFF_FOLD + 176 + t], 0.f);
    }
    __syncthreads();
    float s = 0.f;
#pragma unroll
    for (int j = 0; j < 16; ++j) s += ws[OFF_GW2 + t * 16 + j] * t1[j];
    float* xg = (float*)((char*)ws + XG_BYTES_OFF);
    xg[b * 64 + t] = ws[OFF_FOLD + 192 + t] * s + ws[OFF_FOLD + 256 + t];
}

// ---------------------------------------------------------------------------
// gate slow path (fp32 insurance): one pixel per thread (tid<64 active).
// grid 512 x 256: block = 64 px of one image. xg precomputed -> no barriers.
// ---------------------------------------------------------------------------
__device__ void gate_slow_f32(const void* __restrict__ xv, float* __restrict__ ws,
                              uint4* __restrict__ xo)
{
    int bx = blockIdx.x;
    int b = bx >> 6;
    int tid = threadIdx.x;
    if (tid >= 64) return;
    int n = (bx & 63) * 64 + tid;
    const float* xg = (const float*)((const char*)ws + XG_BYTES_OFF) + b * 64;

    const float* xb = (const float*)xv + (size_t)b * 64 * NPIX + n;
    float xr[64];
#pragma unroll
    for (int c = 0; c < 64; ++c) xr[c] = xb[c * NPIX];

    float h[16];
#pragma unroll
    for (int i = 0; i < 16; ++i) {
        float s = 0.f;
#pragma unroll
        for (int c = 0; c < 64; ++c) s += ws[OFF_LW1 + i * 64 + c] * xr[c];
        h[i] = fmaxf(ws[OFF_FOLD + 0 + i] * s + ws[OFF_FOLD + 16 + i], 0.f);
    }

    uint4* xop = xo + ((size_t)b * NPIX + n) * 8;
#pragma unroll
    for (int cg = 0; cg < 8; ++cg) {
        unsigned v[8];
#pragma unroll
        for (int j = 0; j < 8; ++j) {
            int c = cg * 8 + j;
            float s = 0.f;
#pragma unroll
            for (int k = 0; k < 16; ++k) s += ws[OFF_LW2 + k * 64 + c] * h[k];
            float z = ws[OFF_FOLD + 32 + c] * s + ws[OFF_FOLD + 96 + c] + xg[c];
            v[j] = (unsigned)f2bu(xr[c] / (1.0f + __expf(-z)));
        }
        uint4 pk;
        pk.x = v[0] | (v[1] << 16);
        pk.y = v[2] | (v[3] << 16);
        pk.z = v[4] | (v[5] << 16);
        pk.w = v[6] | (v[7] << 16);
        xop[cg] = pk;
    }
}

// ---------------------------------------------------------------------------
// gate fast path (bf16): weight-stationary MFMA, TLP-fixed (R5 post-mortem:
// duration ~ 1/waves for this latency-bound kernel; r9's 1024 waves -> 265us).
// grid 512 x 256 = 2048 waves (2/SIMD), each wave owns ONE 16-px tile.
// No LDS, no barriers: xg precomputed by r10_xg. Tile body identical to r9
// (hardware-verified correct in R5):
//   layer1: acc = mfma_16x16x32(W1frag_s, Xfrag_s), s=0,1 (K=64)
//   layer2: H C-layout == B-layout of mfma_16x16x16 -> in-lane relu+cvt,
//           4 MFMAs -> Z[c=g*16+4q+reg][px=a]
// ---------------------------------------------------------------------------
__global__ __launch_bounds__(256)
void r10_gate(const void* __restrict__ xv, float* __restrict__ ws,
              uint4* __restrict__ xo)
{
    if (((const int*)ws)[0] != 1) { gate_slow_f32(xv, ws, xo); return; }

    int tid = threadIdx.x;
    int w   = tid >> 6;
    int l   = tid & 63;
    int a   = l & 15;
    int q   = l >> 4;
    int ti  = blockIdx.x * 4 + w;    // 0..2047 tile index
    int b   = ti >> 8;
    int pxl = (ti & 255) * 16 + a;

    const unsigned short* xb = (const unsigned short*)xv + (size_t)b * 64 * NPIX;

    // issue the deep-latency gathers first: lane holds X[c=s*32+q*8+j][pxl]
    unsigned short g0[8], g1[8];
#pragma unroll
    for (int j = 0; j < 8; ++j) {
        g0[j] = xb[(q * 8 + j) * NPIX + pxl];
        g1[j] = xb[(32 + q * 8 + j) * NPIX + pxl];
    }

    // weight frags (L2/L1-hot, every block reads the same 4 KB)
    const unsigned short* gwf =
        (const unsigned short*)((const char*)ws + GWF_BYTES_OFF);
    bf16x8 W1f0 = ((const bf16x8*)gwf)[l];
    bf16x8 W1f1 = ((const bf16x8*)gwf)[64 + l];
    const bf16x4* wf2 = (const bf16x4*)(gwf + 1024);
    bf16x4 W2f0 = wf2[l];
    bf16x4 W2f1 = wf2[64 + l];
    bf16x4 W2f2 = wf2[128 + l];
    bf16x4 W2f3 = wf2[192 + l];

    // per-lane fold consts: layer1 rows i=4q+reg, layer2 ch c=g*16+4q+reg
    float A1v[4], B1v[4];
#pragma unroll
    for (int reg = 0; reg < 4; ++reg) {
        A1v[reg] = ws[OFF_FOLD + 0  + 4 * q + reg];
        B1v[reg] = ws[OFF_FOLD + 16 + 4 * q + reg];
    }
    const float* xgp = (const float*)((const char*)ws + XG_BYTES_OFF) + b * 64;
    float A2v[4][4], B2v[4][4], xgv[4][4];
#pragma unroll
    for (int g = 0; g < 4; ++g)
#pragma unroll
        for (int reg = 0; reg < 4; ++reg) {
            int c = g * 16 + 4 * q + reg;
            A2v[g][reg] = ws[OFF_FOLD + 32 + c];
            B2v[g][reg] = ws[OFF_FOLD + 96 + c];
            xgv[g][reg] = xgp[c];
        }

    const f32x4 zz = {0.f, 0.f, 0.f, 0.f};

    bf16x8 B0 = { (short)g0[0], (short)g0[1], (short)g0[2], (short)g0[3],
                  (short)g0[4], (short)g0[5], (short)g0[6], (short)g0[7] };
    bf16x8 B1 = { (short)g1[0], (short)g1[1], (short)g1[2], (short)g1[3],
                  (short)g1[4], (short)g1[5], (short)g1[6], (short)g1[7] };

    f32x4 acc = __builtin_amdgcn_mfma_f32_16x16x32_bf16(W1f0, B0, zz, 0, 0, 0);
    acc = __builtin_amdgcn_mfma_f32_16x16x32_bf16(W1f1, B1, acc, 0, 0, 0);

    // relu + BN fold, convert in-lane to layer-2 B-frag (k = 4q+j <-> reg)
    bf16x4 Hf = { (short)f2bu(fmaxf(acc[0] * A1v[0] + B1v[0], 0.f)),
                  (short)f2bu(fmaxf(acc[1] * A1v[1] + B1v[1], 0.f)),
                  (short)f2bu(fmaxf(acc[2] * A1v[2] + B1v[2], 0.f)),
                  (short)f2bu(fmaxf(acc[3] * A1v[3] + B1v[3], 0.f)) };

    f32x4 z0 = MFMA16(W2f0, Hf, zz);
    f32x4 z1 = MFMA16(W2f1, Hf, zz);
    f32x4 z2 = MFMA16(W2f2, Hf, zz);
    f32x4 z3 = MFMA16(W2f3, Hf, zz);

    // gating + packed stores: per g, 4 adjacent channels -> one dwordx2
    char* rec = (char*)xo + (size_t)b * NPIX * 128 + (size_t)pxl * 128 + q * 8;
#pragma unroll
    for (int g = 0; g < 4; ++g) {
        const f32x4& zf = (g == 0) ? z0 : (g == 1) ? z1 : (g == 2) ? z2 : z3;
        unsigned vv[4];
#pragma unroll
        for (int reg = 0; reg < 4; ++reg) {
            int c = g * 16 + 4 * q + reg;
            float zval = zf[reg] * A2v[g][reg] + B2v[g][reg] + xgv[g][reg];
            float xval = bu2f(xb[c * NPIX + pxl]);
            vv[reg] = (unsigned)f2bu(xval / (1.0f + __expf(-zval)));
        }
        uint2 pk;
        pk.x = vv[0] | (vv[1] << 16);
        pk.y = vv[2] | (vv[3] << 16);
        *(uint2*)(rec + g * 32) = pk;
    }
}

// ---------------------------------------------------------------------------
// conv3x3 as implicit GEMM on MFMA 16x16x32 bf16 (unchanged, proven).
// Tile: 32 pixels (half image-row) x 64 oc. WG = 128 thr = 2 waves; wave w
// handles oc groups {2w, 2w+1}. Grid = 8 img * 64 rows * 2 halves = 1024 WGs.
// xo B-operands staged in LDS (3 rows x 34 px x 128 B, XOR-swizzled
// byte ^= (px&7)<<4) with zero-filled column halos; conflict-free ds_read_b128.
// C/D layout (m89): col(n=pixel)=lane&15, row(m=oc)=(lane>>4)*4+reg.
// ---------------------------------------------------------------------------
#define CONV_LDS_BYTES (3 * 34 * 128)   // 13056 B

template<typename T>
__device__ void conv_body(const bf16x8* __restrict__ wsw, const float* __restrict__ ws,
                          const char* __restrict__ xob_base, void* __restrict__ outv,
                          char* __restrict__ lds)
{
    int bx  = blockIdx.x;
    int b   = bx >> 7;
    int r   = (bx >> 1) & 63;
    int c0  = (bx & 1) * 32;
    int tid = threadIdx.x;
    int w   = tid >> 6;
    int l   = tid & 63;
    int a   = l & 15;
    int q   = l >> 4;

    const char* xob = xob_base + (size_t)b * NPIX * 128;  // 128 B per pixel

    // ---- stage 3 rows x 34 px (cols c0-1 .. c0+32) of xo, halo cols zeroed.
    for (int e = tid; e < 816; e += 128) {
        int row = e / 272;            // 0..2  (272 = 34 px * 8 chunks)
        int rm  = e - row * 272;
        int px  = rm >> 3;            // 0..33
        int u   = rm & 7;
        int col = c0 - 1 + px;
        int rr  = r - 1 + row;
        uint4 v = {0u, 0u, 0u, 0u};
        if (col >= 0 && col <= 63) {
            int rc = min(63, max(0, rr));   // clamped rows: data unused (tap skipped)
            v = *(const uint4*)(xob + rc * 8192 + col * 128 + u * 16);
        }
        int byt = ((row * 34 + px) * 128 + u * 16) ^ ((px & 7) << 4);
        *(uint4*)(lds + byt) = v;
    }
    __syncthreads();

    f32x4 acc[2][2] = {};   // [oc-group-half][pixel-nf]

#pragma unroll
    for (int t = 0; t < 9; ++t) {
        const int dr  = t / 3 - 1;
        const int dci = t % 3;
        int rr = r + dr;
        if (rr < 0 || rr > 63) continue;           // uniform per WG
        const char* rowp = lds + (dr + 1) * (34 * 128);
#pragma unroll
        for (int s = 0; s < 2; ++s) {
            bf16x8 A0 = wsw[((t * 2 + s) * 4 + 2 * w + 0) * 64 + l];
            bf16x8 A1 = wsw[((t * 2 + s) * 4 + 2 * w + 1) * 64 + l];
            int sq = s * 64 + q * 16;
#pragma unroll
            for (int nf = 0; nf < 2; ++nf) {
                int tp  = nf * 16 + a + dci;       // tile pixel 0..33
                int byt = tp * 128 + (sq ^ ((tp & 7) << 4));
                bf16x8 B = *(const bf16x8*)(rowp + byt);
                acc[0][nf] = __builtin_amdgcn_mfma_f32_16x16x32_bf16(A0, B, acc[0][nf], 0, 0, 0);
                acc[1][nf] = __builtin_amdgcn_mfma_f32_16x16x32_bf16(A1, B, acc[1][nf], 0, 0, 0);
            }
        }
    }

    const float* cA = ws + OFF_FOLD + 320;
    const float* cB = ws + OFF_FOLD + 384;
    int pixBase = r * 64 + c0;
#pragma unroll
    for (int gi = 0; gi < 2; ++gi) {
        int g = 2 * w + gi;
#pragma unroll
        for (int reg = 0; reg < 4; ++reg) {
            int oc = g * 16 + q * 4 + reg;
            float Af = cA[oc];
            float Bf = cB[oc];
#pragma unroll
            for (int nf = 0; nf < 2; ++nf) {
                int pix = pixBase + nf * 16 + a;
                float y = fmaxf(acc[gi][nf][reg] * Af + Bf, 0.f);
                stf((T*)outv + ((size_t)b * 64 + oc) * NPIX + pix, y);
            }
        }
    }
}

__global__ __launch_bounds__(128)
void r10_conv(const bf16x8* __restrict__ wsw, const float* __restrict__ ws,
              const char* __restrict__ xob_base, void* __restrict__ outv)
{
    __shared__ char lds[CONV_LDS_BYTES];
    if (((const int*)ws)[0] == 1) conv_body<bf16>(wsw, ws, xob_base, outv, lds);
    else                          conv_body<float>(wsw, ws, xob_base, outv, lds);
}

// ---------------------------------------------------------------------------
extern "C" void kernel_launch(void* const* d_in, const int* in_sizes, int n_in,
                              void* d_out, int out_size, void* d_ws, size_t ws_size,
                              hipStream_t stream)
{
    (void)in_sizes; (void)n_in; (void)out_size; (void)ws_size;
    const void* x = d_in[0];
    float* ws = (float*)d_ws;
    unsigned short* wswz = (unsigned short*)((char*)d_ws + WSWZ_BYTES_OFF);
    unsigned short* gwf  = (unsigned short*)((char*)d_ws + GWF_BYTES_OFF);
    char* xo = (char*)d_ws + XO_BYTES_OFF;

    PrepArgs7 pa;
    // lw1..lv2 = d_in[1..12], gw1..gv2 = d_in[13..24]
    for (int i = 0; i < 24; ++i) pa.p[i] = d_in[1 + i];
    // d_in[25..31]: qw qb kw kb vw vb gamma -> dead code (attention output discarded)
    for (int i = 0; i < 6; ++i)  pa.p[24 + i] = d_in[32 + i];

    r10_prep_means<<<dim3(531), dim3(256), 0, stream>>>(pa, x, ws, wswz, gwf);
    r10_xg<<<dim3(8), dim3(64), 0, stream>>>(ws);
    r10_gate<<<dim3(512), dim3(256), 0, stream>>>(x, ws, (uint4*)xo);
    r10_conv<<<dim3(1024), dim3(128), 0, stream>>>(
        (const bf16x8*)wswz, ws, xo, d_out);
}

// Round 9
// 184.529 us; speedup vs baseline: 2.0250x; 1.2016x over previous
//
#include <hip/hip_runtime.h>
#include <hip/hip_bf16.h>

// Problem dims: B=8, C=64, H=W=64, INTER=16. Attention branch is dead code
// (its result feeds only the discarded `_dead` tensor).
#define NPIX 4096
#define FEPS 1e-5f

typedef __hip_bfloat16 bf16;
typedef __attribute__((ext_vector_type(8))) short bf16x8;  // 8 bf16 = 4 VGPRs
typedef __attribute__((ext_vector_type(4))) float f32x4;   // MFMA 16x16 acc

// ws layout:
//  word 0 (as int): dtype flag (1 = bf16, 2 = fp32), published by fused k1
//  float region (element offsets):
#define OFF_FOLD 64     // A1[16] B1[16] A2[64](@32) B2[64](@96) gA1(@160) gB1(@176) gA2(@192) gB2(@256) cA(@320) cB(@384)
#define OFF_G    512    // 512 floats: per (b,c) channel means
#define OFF_LW1  1024
#define OFF_LW2  2048   // plain [c][k] layout (R1-proven)
#define OFF_GW1  3072
#define OFF_GW2  4096   // float region ends at 5120 floats = 20480 B
//  byte offsets:
#define WSWZ_BYTES_OFF 20480    // 36864 ushort (73728 B): conv W in MFMA A-frag order
#define XO_BYTES_OFF   94208    // bf16 xo[8][4096 pix][64 ic] (pixel-major), 4 MB
#define XG_BYTES_OFF   4288512  // xg[8][64] fp32 (2 KB), written by r12_xg

template<typename T> __device__ __forceinline__ float ldf(const T* p);
template<> __device__ __forceinline__ float ldf<bf16>(const bf16* p)  { return __bfloat162float(*p); }
template<> __device__ __forceinline__ float ldf<float>(const float* p){ return *p; }

template<typename T> __device__ __forceinline__ void stf(T* p, float v);
template<> __device__ __forceinline__ void stf<bf16>(bf16* p, float v)  { *p = __float2bfloat16(v); }
template<> __device__ __forceinline__ void stf<float>(float* p, float v){ *p = v; }

__device__ __forceinline__ unsigned short f2bu(float f) {
    union { bf16 h; unsigned short u; } c; c.h = __float2bfloat16(f); return c.u;
}
__device__ __forceinline__ float blo(unsigned u) {
    union { unsigned i; float f; } c; c.i = u << 16; return c.f;
}
__device__ __forceinline__ float bhi(unsigned u) {
    union { unsigned i; float f; } c; c.i = u & 0xffff0000u; return c.f;
}

// dtype probe: low 16 bits of each 32-bit word of N(0,1) bf16 data are a bf16
// value (exponent near 127); for fp32 data they are uniform mantissa bits.
__device__ __forceinline__ int probe_flag(const unsigned* __restrict__ x,
                                          int tid, int* sflag)
{
    if (tid < 64) {
        unsigned w = x[tid];
        unsigned h = w & 0xffffu;
        int e = (int)((h >> 7) & 0xff);
        int hit = (h == 0u || (e >= 96 && e <= 160)) ? 1 : 0;
        unsigned long long m = __ballot(hit);
        if (tid == 0) *sflag = (__popcll(m) >= 40) ? 1 : 2;  // bf16 ~64, fp32 ~16
    }
    __syncthreads();
    return *sflag;
}

// ---------------------------------------------------------------------------
struct PrepArgs7 { const void* p[30]; };
// slots: 0..5 lw1 lb1 ls1 lbb1 lm1 lv1 | 6..11 lw2 lb2 ls2 lbb2 lm2 lv2
//        12..17 gw1 gb1 gs1 gbb1 gm1 gv1 | 18..23 gw2 gb2 gs2 gbb2 gm2 gv2
//        24..29 cw cb cs cbb cm cv

// prep body (blocks 0..17): 0..15 swizzle conv W into MFMA A-frag order:
//   wswz[(((t*2+s)*4+g)*64 + l)*8 + j] = cw[oc=g*16+(l&15)][ic=s*32+(l>>4)*8+j][t]
// block 16: gate MLP weights -> fp32 (plain layouts); block 17: BN folds + flag.
template<typename T>
__device__ void prep_body(const PrepArgs7& a, float* __restrict__ ws,
                          unsigned short* __restrict__ wswz, int flag)
{
    const T* lw1  = (const T*)a.p[0];  const T* lb1  = (const T*)a.p[1];
    const T* ls1  = (const T*)a.p[2];  const T* lbb1 = (const T*)a.p[3];
    const T* lm1  = (const T*)a.p[4];  const T* lv1  = (const T*)a.p[5];
    const T* lw2  = (const T*)a.p[6];  const T* lb2  = (const T*)a.p[7];
    const T* ls2  = (const T*)a.p[8];  const T* lbb2 = (const T*)a.p[9];
    const T* lm2  = (const T*)a.p[10]; const T* lv2  = (const T*)a.p[11];
    const T* gw1  = (const T*)a.p[12]; const T* gb1  = (const T*)a.p[13];
    const T* gs1  = (const T*)a.p[14]; const T* gbb1 = (const T*)a.p[15];
    const T* gm1  = (const T*)a.p[16]; const T* gv1  = (const T*)a.p[17];
    const T* gw2  = (const T*)a.p[18]; const T* gb2  = (const T*)a.p[19];
    const T* gs2  = (const T*)a.p[20]; const T* gbb2 = (const T*)a.p[21];
    const T* gm2  = (const T*)a.p[22]; const T* gv2  = (const T*)a.p[23];
    const T* cw   = (const T*)a.p[24]; const T* cb   = (const T*)a.p[25];
    const T* cs   = (const T*)a.p[26]; const T* cbb  = (const T*)a.p[27];
    const T* cm   = (const T*)a.p[28]; const T* cv   = (const T*)a.p[29];

    int bx = blockIdx.x;
    int tid = threadIdx.x;
    if (bx < 16) {
        for (int e = tid; e < 2304; e += 256) {
            int E = bx * 2304 + e;
            int j = E & 7;
            int F = E >> 3;
            int l = F & 63;
            int g = (F >> 6) & 3;
            int ts = F >> 8;          // t*2+s
            int s = ts & 1;
            int t = ts >> 1;
            int oc = g * 16 + (l & 15);
            int ic = s * 32 + (l >> 4) * 8 + j;
            wswz[E] = f2bu(ldf(cw + (oc * 64 + ic) * 9 + t));
        }
    } else if (bx == 16) {
        for (int e = tid; e < 4096; e += 256) {
            if (e < 1024)      ws[OFF_LW1 + e]        = ldf(lw1 + e);
            else if (e < 2048) ws[OFF_LW2 + e - 1024] = ldf(lw2 + e - 1024);
            else if (e < 3072) ws[OFF_GW1 + e - 2048] = ldf(gw1 + e - 2048);
            else               ws[OFF_GW2 + e - 3072] = ldf(gw2 + e - 3072);
        }
    } else {
        if (tid == 0) ((int*)ws)[0] = flag;   // publish for gate/conv kernels
        if (tid < 16) {
            float inv = ldf(ls1 + tid) * rsqrtf(ldf(lv1 + tid) + FEPS);
            ws[OFF_FOLD + 0  + tid] = inv;
            ws[OFF_FOLD + 16 + tid] = ldf(lb1 + tid) * inv + ldf(lbb1 + tid) - ldf(lm1 + tid) * inv;
            float ginv = ldf(gs1 + tid) * rsqrtf(ldf(gv1 + tid) + FEPS);
            ws[OFF_FOLD + 160 + tid] = ginv;
            ws[OFF_FOLD + 176 + tid] = ldf(gb1 + tid) * ginv + ldf(gbb1 + tid) - ldf(gm1 + tid) * ginv;
        }
        if (tid < 64) {
            float inv2 = ldf(ls2 + tid) * rsqrtf(ldf(lv2 + tid) + FEPS);
            ws[OFF_FOLD + 32 + tid] = inv2;
            ws[OFF_FOLD + 96 + tid] = ldf(lb2 + tid) * inv2 + ldf(lbb2 + tid) - ldf(lm2 + tid) * inv2;
            float ginv2 = ldf(gs2 + tid) * rsqrtf(ldf(gv2 + tid) + FEPS);
            ws[OFF_FOLD + 192 + tid] = ginv2;
            ws[OFF_FOLD + 256 + tid] = ldf(gb2 + tid) * ginv2 + ldf(gbb2 + tid) - ldf(gm2 + tid) * ginv2;
            float cinv = ldf(cs + tid) * rsqrtf(ldf(cv + tid) + FEPS);
            ws[OFF_FOLD + 320 + tid] = cinv;
            ws[OFF_FOLD + 384 + tid] = ldf(cb + tid) * cinv + ldf(cbb + tid) - ldf(cm + tid) * cinv;
        }
    }
}

// ---------------------------------------------------------------------------
// fused k1: grid 530 x 256. Every block self-probes the dtype (cheap, L2-hot).
//  blocks 0..17  : prep (weight swizzle / MLP weights / BN folds + flag)
//  blocks 18..529: channel mean for bc = bx-18 (vectorized loads)
// ---------------------------------------------------------------------------
__global__ void r12_prep_means(PrepArgs7 a, const void* __restrict__ xv,
                               float* __restrict__ ws,
                               unsigned short* __restrict__ wswz)
{
    __shared__ int sflag;
    int t = threadIdx.x;
    int flag = probe_flag((const unsigned*)xv, t, &sflag);
    int bx = blockIdx.x;

    if (bx < 18) {
        if (flag == 1) prep_body<bf16>(a, ws, wswz, flag);
        else           prep_body<float>(a, ws, wswz, flag);
        return;
    }

    int bc = bx - 18;
    float s = 0.f;
    if (flag == 1) {
        const uint4* p = (const uint4*)((const bf16*)xv + (size_t)bc * NPIX);
#pragma unroll
        for (int i = 0; i < 2; ++i) {
            uint4 v = p[t * 2 + i];
            s += blo(v.x) + bhi(v.x) + blo(v.y) + bhi(v.y)
               + blo(v.z) + bhi(v.z) + blo(v.w) + bhi(v.w);
        }
    } else {
        const float4* p = (const float4*)((const float*)xv + (size_t)bc * NPIX);
#pragma unroll
        for (int i = 0; i < 4; ++i) {
            float4 v = p[t * 4 + i];
            s += v.x + v.y + v.z + v.w;
        }
    }
#pragma unroll
    for (int off = 32; off > 0; off >>= 1) s += __shfl_down(s, off, 64);
    __shared__ float red[4];
    if ((t & 63) == 0) red[t >> 6] = s;
    __syncthreads();
    if (t == 0)
        ws[OFF_G + bc] = (red[0] + red[1] + red[2] + red[3]) * (1.0f / 4096.0f);
}

// ---------------------------------------------------------------------------
// xg one-shot (r10-proven-safe hoist): global-branch MLP depends only on
// per-image means -> compute ONCE (8 blocks x 64 thr). Math identical to the
// R1 in-gate t1/xg phases. Dtype-agnostic: reads prep's fp32 copies.
// ---------------------------------------------------------------------------
__global__ void r12_xg(float* __restrict__ ws)
{
    int b = blockIdx.x;
    int t = threadIdx.x;
    __shared__ float t1[16];
    if (t < 16) {
        float s = 0.f;
#pragma unroll
        for (int c = 0; c < 64; ++c)
            s += ws[OFF_GW1 + t * 64 + c] * ws[OFF_G + b * 64 + c];
        t1[t] = fmaxf(ws[OFF_FOLD + 160 + t] * s + ws[OFF_FOLD + 176 + t], 0.f);
    }
    __syncthreads();
    float s = 0.f;
#pragma unroll
    for (int j = 0; j < 16; ++j) s += ws[OFF_GW2 + t * 16 + j] * t1[j];
    float* xg = (float*)((char*)ws + XG_BYTES_OFF);
    xg[b * 64 + t] = ws[OFF_FOLD + 192 + t] * s + ws[OFF_FOLD + 256 + t];
}

// ---------------------------------------------------------------------------
// gate slow path (fp32 insurance): one pixel per thread. grid 256 x 128.
// xg precomputed by r12_xg (scalar-uniform global reads), no barriers.
// ---------------------------------------------------------------------------
__device__ void gate_slow_f32(const void* __restrict__ xv, float* __restrict__ ws,
                              uint4* __restrict__ xo)
{
    int b = blockIdx.x >> 5;
    int n = (blockIdx.x & 31) * 128 + threadIdx.x;
    const float* xg = (const float*)((const char*)ws + XG_BYTES_OFF) + b * 64;

    const float* xb = (const float*)xv + (size_t)b * 64 * NPIX + n;
    float xr[64];
#pragma unroll
    for (int c = 0; c < 64; ++c) xr[c] = xb[c * NPIX];

    float h[16];
#pragma unroll
    for (int i = 0; i < 16; ++i) {
        float s = 0.f;
#pragma unroll
        for (int c = 0; c < 64; ++c) s += ws[OFF_LW1 + i * 64 + c] * xr[c];
        h[i] = fmaxf(ws[OFF_FOLD + 0 + i] * s + ws[OFF_FOLD + 16 + i], 0.f);
    }

    uint4* xop = xo + ((size_t)b * NPIX + n) * 8;
#pragma unroll
    for (int cg = 0; cg < 8; ++cg) {
        unsigned v[8];
#pragma unroll
        for (int j = 0; j < 8; ++j) {
            int c = cg * 8 + j;
            float s = 0.f;
#pragma unroll
            for (int k = 0; k < 16; ++k) s += ws[OFF_LW2 + c * 16 + k] * h[k];
            float z = ws[OFF_FOLD + 32 + c] * s + ws[OFF_FOLD + 96 + c] + xg[c];
            v[j] = (unsigned)f2bu(xr[c] / (1.0f + __expf(-z)));
        }
        uint4 pk;
        pk.x = v[0] | (v[1] << 16);
        pk.y = v[2] | (v[3] << 16);
        pk.z = v[4] | (v[5] << 16);
        pk.w = v[6] | (v[7] << 16);
        xop[cg] = pk;
    }
}

// ---------------------------------------------------------------------------
// gate fast path (bf16): the R1-PROVEN structure byte-for-byte — same tile,
// same in-tile pack round-trip, same THREE barriers — with exactly one graft
// (R7 post-mortem, minimal-delta isolation): the serial t1/xg phases are
// replaced by a 64-lane cooperative load of precomputed xg from global,
// slotted before the existing stage barrier (zero new barriers).
// grid 256 x 128: block = 128 px of one image, thread = 1 pixel.
// ---------------------------------------------------------------------------
__global__ __launch_bounds__(128)
void r12_gate(const void* __restrict__ xv, float* __restrict__ ws,
              uint4* __restrict__ xo)
{
    if (((const int*)ws)[0] != 1) { gate_slow_f32(xv, ws, xo); return; }

    int bx = blockIdx.x;
    int b = bx >> 5;
    int pix0 = (bx & 31) * 128;
    int t = threadIdx.x;

    __shared__ float xg[64];
    __shared__ char tile[64 * 256];   // [c][128 px] bf16, row stride 256 B

    // 1. issue coalesced tile loads (8 independent uint4 / thread)
    const uint4* xsrc = (const uint4*)((const bf16*)xv + (size_t)b * 64 * NPIX + pix0);
    uint4 ld[8];
#pragma unroll
    for (int k = 0; k < 8; ++k) {
        int e = k * 128 + t;          // 0..1023
        int c = e >> 4;               // 16 uint4 per 128-px row
        int u = e & 15;
        ld[k] = xsrc[(size_t)c * 512 + u];
    }
    // 2. overlap: fetch precomputed xg (replaces R1's serial t1 phase)
    if (t < 64)
        xg[t] = ((const float*)((const char*)ws + XG_BYTES_OFF))[b * 64 + t];
    // 3. stage tile
#pragma unroll
    for (int k = 0; k < 8; ++k) {
        int e = k * 128 + t;
        int c = e >> 4;
        int u = e & 15;
        *(uint4*)(tile + c * 256 + u * 16) = ld[k];
    }
    __syncthreads();   // tile staged + xg visible
    // 4. per-pixel column read
    float xr[64];
#pragma unroll
    for (int c = 0; c < 64; ++c)
        xr[c] = __bfloat162float(*(const bf16*)(tile + c * 256 + t * 2));
    // 5. local MLP layer 1
    float h[16];
#pragma unroll
    for (int i = 0; i < 16; ++i) {
        float s = 0.f;
#pragma unroll
        for (int c = 0; c < 64; ++c) s += ws[OFF_LW1 + i * 64 + c] * xr[c];
        h[i] = fmaxf(ws[OFF_FOLD + 0 + i] * s + ws[OFF_FOLD + 16 + i], 0.f);
    }
    __syncthreads();   // all tile reads (step 4) complete before repack
    // 6. layer 2 + gating -> pack into tile (swizzled; R1-proven round-trip)
#pragma unroll
    for (int cg = 0; cg < 8; ++cg) {
        unsigned v[8];
#pragma unroll
        for (int j = 0; j < 8; ++j) {
            int c = cg * 8 + j;
            float s = 0.f;
#pragma unroll
            for (int k = 0; k < 16; ++k) s += ws[OFF_LW2 + c * 16 + k] * h[k];
            float z = ws[OFF_FOLD + 32 + c] * s + ws[OFF_FOLD + 96 + c] + xg[c];
            v[j] = (unsigned)f2bu(xr[c] / (1.0f + __expf(-z)));
        }
        uint4 pk;
        pk.x = v[0] | (v[1] << 16);
        pk.y = v[2] | (v[3] << 16);
        pk.z = v[4] | (v[5] << 16);
        pk.w = v[6] | (v[7] << 16);
        *(uint4*)(tile + ((t * 128 + cg * 16) ^ ((t & 7) << 4))) = pk;
    }
    __syncthreads();
    // 7. coalesced copy-out: lane-consecutive uint4 (1 KB per wave store)
    uint4* xop = xo + ((size_t)b * NPIX + pix0) * 8;
#pragma unroll
    for (int k = 0; k < 8; ++k) {
        int e = k * 128 + t;
        int p = e >> 3;
        int u = e & 7;
        xop[e] = *(const uint4*)(tile + ((p * 128 + u * 16) ^ ((p & 7) << 4)));
    }
}

// ---------------------------------------------------------------------------
// conv3x3 as implicit GEMM on MFMA 16x16x32 bf16 (unchanged, proven R1).
// Tile: 32 pixels (half image-row) x 64 oc. WG = 128 thr = 2 waves; wave w
// handles oc groups {2w, 2w+1}. Grid = 8 img * 64 rows * 2 halves = 1024 WGs.
// xo B-operands staged in LDS (3 rows x 34 px x 128 B, XOR-swizzled
// byte ^= (px&7)<<4) with zero-filled column halos; conflict-free ds_read_b128.
// C/D layout (m89): col(n=pixel)=lane&15, row(m=oc)=(lane>>4)*4+reg.
// ---------------------------------------------------------------------------
#define CONV_LDS_BYTES (3 * 34 * 128)   // 13056 B

template<typename T>
__device__ void conv_body(const bf16x8* __restrict__ wsw, const float* __restrict__ ws,
                          const char* __restrict__ xob_base, void* __restrict__ outv,
                          char* __restrict__ lds)
{
    int bx  = blockIdx.x;
    int b   = bx >> 7;
    int r   = (bx >> 1) & 63;
    int c0  = (bx & 1) * 32;
    int tid = threadIdx.x;
    int w   = tid >> 6;
    int l   = tid & 63;
    int a   = l & 15;
    int q   = l >> 4;

    const char* xob = xob_base + (size_t)b * NPIX * 128;  // 128 B per pixel

    // ---- stage 3 rows x 34 px (cols c0-1 .. c0+32) of xo, halo cols zeroed.
    for (int e = tid; e < 816; e += 128) {
        int row = e / 272;            // 0..2  (272 = 34 px * 8 chunks)
        int rm  = e - row * 272;
        int px  = rm >> 3;            // 0..33
        int u   = rm & 7;
        int col = c0 - 1 + px;
        int rr  = r - 1 + row;
        uint4 v = {0u, 0u, 0u, 0u};
        if (col >= 0 && col <= 63) {
            int rc = min(63, max(0, rr));   // clamped rows: data unused (tap skipped)
            v = *(const uint4*)(xob + rc * 8192 + col * 128 + u * 16);
        }
        int byt = ((row * 34 + px) * 128 + u * 16) ^ ((px & 7) << 4);
        *(uint4*)(lds + byt) = v;
    }
    __syncthreads();

    f32x4 acc[2][2] = {};   // [oc-group-half][pixel-nf]

#pragma unroll
    for (int t = 0; t < 9; ++t) {
        const int dr  = t / 3 - 1;
        const int dci = t % 3;
        int rr = r + dr;
        if (rr < 0 || rr > 63) continue;           // uniform per WG
        const char* rowp = lds + (dr + 1) * (34 * 128);
#pragma unroll
        for (int s = 0; s < 2; ++s) {
            bf16x8 A0 = wsw[((t * 2 + s) * 4 + 2 * w + 0) * 64 + l];
            bf16x8 A1 = wsw[((t * 2 + s) * 4 + 2 * w + 1) * 64 + l];
            int sq = s * 64 + q * 16;
#pragma unroll
            for (int nf = 0; nf < 2; ++nf) {
                int tp  = nf * 16 + a + dci;       // tile pixel 0..33
                int byt = tp * 128 + (sq ^ ((tp & 7) << 4));
                bf16x8 B = *(const bf16x8*)(rowp + byt);
                acc[0][nf] = __builtin_amdgcn_mfma_f32_16x16x32_bf16(A0, B, acc[0][nf], 0, 0, 0);
                acc[1][nf] = __builtin_amdgcn_mfma_f32_16x16x32_bf16(A1, B, acc[1][nf], 0, 0, 0);
            }
        }
    }

    const float* cA = ws + OFF_FOLD + 320;
    const float* cB = ws + OFF_FOLD + 384;
    int pixBase = r * 64 + c0;
#pragma unroll
    for (int gi = 0; gi < 2; ++gi) {
        int g = 2 * w + gi;
#pragma unroll
        for (int reg = 0; reg < 4; ++reg) {
            int oc = g * 16 + q * 4 + reg;
            float Af = cA[oc];
            float Bf = cB[oc];
#pragma unroll
            for (int nf = 0; nf < 2; ++nf) {
                int pix = pixBase + nf * 16 + a;
                float y = fmaxf(acc[gi][nf][reg] * Af + Bf, 0.f);
                stf((T*)outv + ((size_t)b * 64 + oc) * NPIX + pix, y);
            }
        }
    }
}

__global__ __launch_bounds__(128)
void r12_conv(const bf16x8* __restrict__ wsw, const float* __restrict__ ws,
              const char* __restrict__ xob_base, void* __restrict__ outv)
{
    __shared__ char lds[CONV_LDS_BYTES];
    if (((const int*)ws)[0] == 1) conv_body<bf16>(wsw, ws, xob_base, outv, lds);
    else                          conv_body<float>(wsw, ws, xob_base, outv, lds);
}

// ---------------------------------------------------------------------------
extern "C" void kernel_launch(void* const* d_in, const int* in_sizes, int n_in,
                              void* d_out, int out_size, void* d_ws, size_t ws_size,
                              hipStream_t stream)
{
    (void)in_sizes; (void)n_in; (void)out_size; (void)ws_size;
    const void* x = d_in[0];
    float* ws = (float*)d_ws;
    unsigned short* wswz = (unsigned short*)((char*)d_ws + WSWZ_BYTES_OFF);
    char* xo = (char*)d_ws + XO_BYTES_OFF;

    PrepArgs7 pa;
    // lw1..lv2 = d_in[1..12], gw1..gv2 = d_in[13..24]
    for (int i = 0; i < 24; ++i) pa.p[i] = d_in[1 + i];
    // d_in[25..31]: qw qb kw kb vw vb gamma -> dead code (attention output discarded)
    for (int i = 0; i < 6; ++i)  pa.p[24 + i] = d_in[32 + i];

    r12_prep_means<<<dim3(530), dim3(256), 0, stream>>>(pa, x, ws, wswz);
    r12_xg<<<dim3(8), dim3(64), 0, stream>>>(ws);
    r12_gate<<<dim3(256), dim3(128), 0, stream>>>(x, ws, (uint4*)xo);
    r12_conv<<<dim3(1024), dim3(128), 0, stream>>>(
        (const bf16x8*)wswz, ws, xo, d_out);
}